// Round 9
// baseline (284.550 us; speedup 1.0000x reference)
//
#include <hip/hip_runtime.h>
#include <hip/hip_cooperative_groups.h>
#include <hip/hip_bf16.h>
#include <cstdint>

#define BATCH 256
#define DIN   512
#define D2    128
#define NQ    16
#define NC    100
#define KFC   (D2 * D2)      // 16384

// fallback k_fc config (R8, validated)
#define KS    32
#define KCH   (KFC / KS)     // 512
#define STEPS (KCH / 32)     // 16

// cooperative-kernel FC config
#define FC2_KS    16
#define FC2_KCH   (KFC / FC2_KS)    // 1024
#define FC2_STEPS (FC2_KCH / 32)    // 32

#define ZPAD  132            // Zt/Et row stride (floats)
#define XTP   520            // Xt LDS row stride (bf16)
#define CVT_BLKS 800
#define W2_BLKS  256

namespace cg = cooperative_groups;

typedef short short8 __attribute__((ext_vector_type(8)));
typedef float f32x4  __attribute__((ext_vector_type(4)));
typedef float f32x16 __attribute__((ext_vector_type(16)));

// ---------------------------------------------------------------------------
// Hand-unrolled Gauss-Jordan step (all indices compile-time constant).
// ---------------------------------------------------------------------------
#define GJ_STEP(K) do {                                                   \
    float piv = __shfl(g[(K) & 7], ((K) >> 3) * 16 + (K), 64);            \
    float fac = __shfl(g[(K) & 7], ((K) >> 3) * 16 + r, 64);              \
    float inv = 1.0f / piv;                                               \
    float f   = fac * inv;                                                \
    float p0 = __shfl(g[0], cg16 + (K), 64);                              \
    float p1 = __shfl(g[1], cg16 + (K), 64);                              \
    float p2 = __shfl(g[2], cg16 + (K), 64);                              \
    float p3 = __shfl(g[3], cg16 + (K), 64);                              \
    float p4 = __shfl(g[4], cg16 + (K), 64);                              \
    float p5 = __shfl(g[5], cg16 + (K), 64);                              \
    float p6 = __shfl(g[6], cg16 + (K), 64);                              \
    float p7 = __shfl(g[7], cg16 + (K), 64);                              \
    bool isk = (r == (K));                                                \
    g[0] = isk ? p0 * inv : fmaf(-f, p0, g[0]);                           \
    g[1] = isk ? p1 * inv : fmaf(-f, p1, g[1]);                           \
    g[2] = isk ? p2 * inv : fmaf(-f, p2, g[2]);                           \
    g[3] = isk ? p3 * inv : fmaf(-f, p3, g[3]);                           \
    g[4] = isk ? p4 * inv : fmaf(-f, p4, g[4]);                           \
    g[5] = isk ? p5 * inv : fmaf(-f, p5, g[5]);                           \
    g[6] = isk ? p6 * inv : fmaf(-f, p6, g[6]);                           \
    g[7] = isk ? p7 * inv : fmaf(-f, p7, g[7]);                           \
} while (0)

// ===========================================================================
// Cooperative mega-kernel: prep -> sync -> zgep -> sync -> FC -> sync -> red
// 256 blocks x 512 threads (1 block/CU).
// ===========================================================================
__global__ __launch_bounds__(512) void k_all(const float* __restrict__ X,
                                             const float* __restrict__ W,
                                             const float* __restrict__ fcw,
                                             const float* __restrict__ fcb,
                                             float* __restrict__ out,
                                             __hip_bfloat16* __restrict__ W2hi,
                                             __hip_bfloat16* __restrict__ W2lo,
                                             __hip_bfloat16* __restrict__ P2,
                                             float* __restrict__ part) {
    cg::grid_group grid = cg::this_grid();

    __shared__ float Xs[DIN][17];
    __shared__ __hip_bfloat16 Xthi[NQ][XTP];
    __shared__ __hip_bfloat16 Xtlo[NQ][XTP];
    __shared__ float Zt[NQ][ZPAD];
    __shared__ float Et[NQ][ZPAD];
    __shared__ float Gi[NQ][36];

    int blk = blockIdx.x;
    int t = threadIdx.x;
    int l = t & 63;
    int wv = t >> 6;

    // ---------------- phase A: W2 hi/lo (65536 elems over 256 blocks) ------
    if (t < 256) {
        int idx = blk * 256 + t;
        int o = idx >> 9;
        int i = idx & (DIN - 1);
        float v = 0.5f * (W[(size_t)(2 * o) * DIN + i] +
                          W[(size_t)(2 * o + 1) * DIN + i]);
        __hip_bfloat16 hi = __float2bfloat16(v);
        W2hi[idx] = hi;
        W2lo[idx] = __float2bfloat16(v - __bfloat162float(hi));
    }
    __threadfence();
    grid.sync();

    // ---------------- phase B: per-batch zgep (b = blk) --------------------
    {
        int b = blk;
        // stage X_b
        {
            const float4* src = (const float4*)(X + (size_t)b * DIN * NQ);
            #pragma unroll
            for (int r = 0; r < 4; ++r) {
                float4 v = src[t + r * 512];
                int idx = (t + r * 512) * 4;
                int i = idx >> 4, q = idx & 15;
                Xs[i][q]     = v.x;
                Xs[i][q + 1] = v.y;
                Xs[i][q + 2] = v.z;
                Xs[i][q + 3] = v.w;
            }
        }
        __syncthreads();

        // transpose + hi/lo split
        {
            int q  = t >> 5;
            int li = t & 31;
            #pragma unroll
            for (int c = 0; c < 8; ++c) {
                int i0 = c * 64 + li * 2;
                float v0 = Xs[i0][q], v1 = Xs[i0 + 1][q];
                __hip_bfloat16 h0 = __float2bfloat16(v0);
                __hip_bfloat16 h1 = __float2bfloat16(v1);
                __hip_bfloat16 l0 = __float2bfloat16(v0 - __bfloat162float(h0));
                __hip_bfloat16 l1 = __float2bfloat16(v1 - __bfloat162float(h1));
                Xthi[q][i0] = h0; Xthi[q][i0 + 1] = h1;
                Xtlo[q][i0] = l0; Xtlo[q][i0 + 1] = l1;
            }
        }
        __syncthreads();

        // Z via MFMA, hi/lo compensated
        {
            int m  = l & 15;
            int kg = (l >> 4) * 8;
            const __hip_bfloat16* whi = W2hi + (size_t)(wv * 16 + m) * DIN + kg;
            const __hip_bfloat16* wlo = W2lo + (size_t)(wv * 16 + m) * DIN + kg;
            f32x4 acc = {0.f, 0.f, 0.f, 0.f};
            #pragma unroll 4
            for (int s = 0; s < 16; ++s) {
                short8 ahi = *(const short8*)(whi + s * 32);
                short8 alo = *(const short8*)(wlo + s * 32);
                short8 bhi = *(const short8*)&Xthi[m][s * 32 + kg];
                short8 blo = *(const short8*)&Xtlo[m][s * 32 + kg];
                acc = __builtin_amdgcn_mfma_f32_16x16x32_bf16(ahi, bhi, acc, 0, 0, 0);
                acc = __builtin_amdgcn_mfma_f32_16x16x32_bf16(ahi, blo, acc, 0, 0, 0);
                acc = __builtin_amdgcn_mfma_f32_16x16x32_bf16(alo, bhi, acc, 0, 0, 0);
            }
            int r0 = (l >> 4) * 4;
            #pragma unroll
            for (int j = 0; j < 4; ++j)
                Zt[m][wv * 16 + r0 + j] = acc[j];
        }
        __syncthreads();

        // G = Z^T Z
        if (t < 256) {
            int qq = t >> 4, rr = t & 15;
            float s = 0.f;
            for (int i = 0; i < D2; i += 4) {
                float4 a = *(const float4*)&Zt[qq][i];
                float4 c = *(const float4*)&Zt[rr][i];
                s = fmaf(a.x, c.x, s); s = fmaf(a.y, c.y, s);
                s = fmaf(a.z, c.z, s); s = fmaf(a.w, c.w, s);
            }
            Gi[qq][rr] = s;
            Gi[qq][NQ + rr] = (qq == rr) ? 1.f : 0.f;
        }
        __syncthreads();

        // wave-register Gauss-Jordan
        if (t < 64) {
            int r    = t & 15;
            int cgg  = t >> 4;
            int cg16 = cgg * 16;
            float g[8];
            #pragma unroll
            for (int j = 0; j < 8; ++j) g[j] = Gi[r][cgg * 8 + j];
            GJ_STEP(0);  GJ_STEP(1);  GJ_STEP(2);  GJ_STEP(3);
            GJ_STEP(4);  GJ_STEP(5);  GJ_STEP(6);  GJ_STEP(7);
            GJ_STEP(8);  GJ_STEP(9);  GJ_STEP(10); GJ_STEP(11);
            GJ_STEP(12); GJ_STEP(13); GJ_STEP(14); GJ_STEP(15);
            if (cgg >= 2) {
                #pragma unroll
                for (int j = 0; j < 8; ++j) Gi[r][cgg * 8 + j] = g[j];
            }
        }
        __syncthreads();

        // E = Z G^{-1}
        {
            int o  = t & (D2 - 1);
            int qg = (t >> 7) * 4;
            float acc[4] = {};
            #pragma unroll
            for (int rp = 0; rp < NQ; ++rp) {
                float z = Zt[rp][o];
                #pragma unroll
                for (int j = 0; j < 4; ++j)
                    acc[j] = fmaf(z, Gi[rp][NQ + qg + j], acc[j]);
            }
            #pragma unroll
            for (int j = 0; j < 4; ++j) Et[qg + j][o] = acc[j];
        }
        __syncthreads();

        // P2 = E Z^T via MFMA 32x32x16
        {
            __hip_bfloat16* P2b = P2 + (size_t)b * KFC;
            int ti = wv >> 1;
            int tj0 = (wv & 1) * 2;
            int r8 = (l >> 5) * 8;
            int rm = l & 31;

            short8 afr;
            {
                __hip_bfloat16* ah = (__hip_bfloat16*)&afr;
                #pragma unroll
                for (int j = 0; j < 8; ++j)
                    ah[j] = __float2bfloat16(Et[r8 + j][ti * 32 + rm]);
            }
            #pragma unroll
            for (int tjo = 0; tjo < 2; ++tjo) {
                int tj = tj0 + tjo;
                short8 bfr;
                __hip_bfloat16* bh = (__hip_bfloat16*)&bfr;
                #pragma unroll
                for (int j = 0; j < 8; ++j)
                    bh[j] = __float2bfloat16(Zt[r8 + j][tj * 32 + rm]);
                f32x16 cc = {};
                cc = __builtin_amdgcn_mfma_f32_32x32x16_bf16(afr, bfr, cc, 0, 0, 0);
                #pragma unroll
                for (int reg = 0; reg < 16; ++reg) {
                    int row = (reg & 3) + 8 * (reg >> 2) + 4 * (l >> 5);
                    P2b[(size_t)(ti * 32 + row) * D2 + tj * 32 + rm] =
                        __float2bfloat16(cc[reg]);
                }
            }
        }
    }
    __threadfence();
    grid.sync();

    // ---------------- phase C: FC split-K (bt = blk>>4, ks = blk&15) -------
    {
        int bt = blk >> 4;
        int ks = blk & 15;
        int m  = l & 15;
        int kg = (l >> 4) * 8;

        const __hip_bfloat16* pa =
            P2 + (size_t)(bt * 16 + m) * KFC + ks * FC2_KCH + kg;

        int c = wv * 16 + m;             // 0..127
        bool vc = (c < NC);
        const float* pb = fcw + (size_t)(vc ? c : 0) * KFC + ks * FC2_KCH + kg;

        f32x4 acc = {0.f, 0.f, 0.f, 0.f};
        #pragma unroll 4
        for (int s = 0; s < FC2_STEPS; ++s) {
            short8 a = *(const short8*)(pa + s * 32);
            short8 bb;
            if (vc) {
                float4 b0 = *(const float4*)(pb + s * 32);
                float4 b1 = *(const float4*)(pb + s * 32 + 4);
                __hip_bfloat16* bh = (__hip_bfloat16*)&bb;
                bh[0] = __float2bfloat16(b0.x); bh[1] = __float2bfloat16(b0.y);
                bh[2] = __float2bfloat16(b0.z); bh[3] = __float2bfloat16(b0.w);
                bh[4] = __float2bfloat16(b1.x); bh[5] = __float2bfloat16(b1.y);
                bh[6] = __float2bfloat16(b1.z); bh[7] = __float2bfloat16(b1.w);
            } else {
                bb = short8{};
            }
            acc = __builtin_amdgcn_mfma_f32_16x16x32_bf16(a, bb, acc, 0, 0, 0);
        }

        int r0 = (l >> 4) * 4;
        float* pp = part + ((size_t)ks * BATCH + bt * 16 + r0) * D2 + c;
        #pragma unroll
        for (int j = 0; j < 4; ++j)
            pp[(size_t)j * D2] = acc[j];
    }
    __threadfence();
    grid.sync();

    // ---------------- phase D: reduce + bias (b = blk) ---------------------
    if (t < D2) {
        int b = blk, c = t;
        float s = (c < NC) ? fcb[c] : 0.f;
        #pragma unroll
        for (int ks = 0; ks < FC2_KS; ++ks)
            s += part[((size_t)ks * BATCH + b) * D2 + c];
        if (c < NC) out[(size_t)b * NC + c] = s;
    }
}

// ===========================================================================
// Fallback path: exact R8 4-kernel pipeline (validated), used only if the
// cooperative launch is rejected.
// ===========================================================================
__global__ __launch_bounds__(256) void k_prep(const float* __restrict__ W,
                                              const float* __restrict__ fcw,
                                              __hip_bfloat16* __restrict__ W2hi,
                                              __hip_bfloat16* __restrict__ W2lo,
                                              __hip_bfloat16* __restrict__ fcw16) {
    int blk = blockIdx.x;
    if (blk < CVT_BLKS) {
        int i = (blk * 256 + threadIdx.x) * 8;
        float4 a = *(const float4*)(fcw + i);
        float4 b = *(const float4*)(fcw + i + 4);
        short8 v;
        __hip_bfloat16* h = (__hip_bfloat16*)&v;
        h[0] = __float2bfloat16(a.x); h[1] = __float2bfloat16(a.y);
        h[2] = __float2bfloat16(a.z); h[3] = __float2bfloat16(a.w);
        h[4] = __float2bfloat16(b.x); h[5] = __float2bfloat16(b.y);
        h[6] = __float2bfloat16(b.z); h[7] = __float2bfloat16(b.w);
        *(short8*)(fcw16 + i) = v;
    } else {
        int idx = (blk - CVT_BLKS) * 256 + threadIdx.x;
        int o = idx >> 9;
        int i = idx & (DIN - 1);
        float v = 0.5f * (W[(size_t)(2 * o) * DIN + i] +
                          W[(size_t)(2 * o + 1) * DIN + i]);
        __hip_bfloat16 hi = __float2bfloat16(v);
        W2hi[idx] = hi;
        W2lo[idx] = __float2bfloat16(v - __bfloat162float(hi));
    }
}

__global__ __launch_bounds__(512) void k_zgep(const float* __restrict__ X,
                                              const __hip_bfloat16* __restrict__ W2hi,
                                              const __hip_bfloat16* __restrict__ W2lo,
                                              __hip_bfloat16* __restrict__ P2) {
    __shared__ float Xs[DIN][17];
    __shared__ __hip_bfloat16 Xthi[NQ][XTP];
    __shared__ __hip_bfloat16 Xtlo[NQ][XTP];
    __shared__ float Zt[NQ][ZPAD];
    __shared__ float Et[NQ][ZPAD];
    __shared__ float Gi[NQ][36];

    int b = blockIdx.x;
    int t = threadIdx.x;
    int l = t & 63;
    int wv = t >> 6;

    {
        const float4* src = (const float4*)(X + (size_t)b * DIN * NQ);
        #pragma unroll
        for (int r = 0; r < 4; ++r) {
            float4 v = src[t + r * 512];
            int idx = (t + r * 512) * 4;
            int i = idx >> 4, q = idx & 15;
            Xs[i][q]     = v.x;
            Xs[i][q + 1] = v.y;
            Xs[i][q + 2] = v.z;
            Xs[i][q + 3] = v.w;
        }
    }
    __syncthreads();

    {
        int q  = t >> 5;
        int li = t & 31;
        #pragma unroll
        for (int c = 0; c < 8; ++c) {
            int i0 = c * 64 + li * 2;
            float v0 = Xs[i0][q], v1 = Xs[i0 + 1][q];
            __hip_bfloat16 h0 = __float2bfloat16(v0);
            __hip_bfloat16 h1 = __float2bfloat16(v1);
            __hip_bfloat16 l0 = __float2bfloat16(v0 - __bfloat162float(h0));
            __hip_bfloat16 l1 = __float2bfloat16(v1 - __bfloat162float(h1));
            Xthi[q][i0] = h0; Xthi[q][i0 + 1] = h1;
            Xtlo[q][i0] = l0; Xtlo[q][i0 + 1] = l1;
        }
    }
    __syncthreads();

    {
        int m  = l & 15;
        int kg = (l >> 4) * 8;
        const __hip_bfloat16* whi = W2hi + (size_t)(wv * 16 + m) * DIN + kg;
        const __hip_bfloat16* wlo = W2lo + (size_t)(wv * 16 + m) * DIN + kg;
        f32x4 acc = {0.f, 0.f, 0.f, 0.f};
        #pragma unroll 4
        for (int s = 0; s < 16; ++s) {
            short8 ahi = *(const short8*)(whi + s * 32);
            short8 alo = *(const short8*)(wlo + s * 32);
            short8 bhi = *(const short8*)&Xthi[m][s * 32 + kg];
            short8 blo = *(const short8*)&Xtlo[m][s * 32 + kg];
            acc = __builtin_amdgcn_mfma_f32_16x16x32_bf16(ahi, bhi, acc, 0, 0, 0);
            acc = __builtin_amdgcn_mfma_f32_16x16x32_bf16(ahi, blo, acc, 0, 0, 0);
            acc = __builtin_amdgcn_mfma_f32_16x16x32_bf16(alo, bhi, acc, 0, 0, 0);
        }
        int r0 = (l >> 4) * 4;
        #pragma unroll
        for (int j = 0; j < 4; ++j)
            Zt[m][wv * 16 + r0 + j] = acc[j];
    }
    __syncthreads();

    if (t < 256) {
        int qq = t >> 4, rr = t & 15;
        float s = 0.f;
        for (int i = 0; i < D2; i += 4) {
            float4 a = *(const float4*)&Zt[qq][i];
            float4 c = *(const float4*)&Zt[rr][i];
            s = fmaf(a.x, c.x, s); s = fmaf(a.y, c.y, s);
            s = fmaf(a.z, c.z, s); s = fmaf(a.w, c.w, s);
        }
        Gi[qq][rr] = s;
        Gi[qq][NQ + rr] = (qq == rr) ? 1.f : 0.f;
    }
    __syncthreads();

    if (t < 64) {
        int r    = t & 15;
        int cgg  = t >> 4;
        int cg16 = cgg * 16;
        float g[8];
        #pragma unroll
        for (int j = 0; j < 8; ++j) g[j] = Gi[r][cgg * 8 + j];
        GJ_STEP(0);  GJ_STEP(1);  GJ_STEP(2);  GJ_STEP(3);
        GJ_STEP(4);  GJ_STEP(5);  GJ_STEP(6);  GJ_STEP(7);
        GJ_STEP(8);  GJ_STEP(9);  GJ_STEP(10); GJ_STEP(11);
        GJ_STEP(12); GJ_STEP(13); GJ_STEP(14); GJ_STEP(15);
        if (cgg >= 2) {
            #pragma unroll
            for (int j = 0; j < 8; ++j) Gi[r][cgg * 8 + j] = g[j];
        }
    }
    __syncthreads();

    {
        int o  = t & (D2 - 1);
        int qg = (t >> 7) * 4;
        float acc[4] = {};
        #pragma unroll
        for (int rp = 0; rp < NQ; ++rp) {
            float z = Zt[rp][o];
            #pragma unroll
            for (int j = 0; j < 4; ++j)
                acc[j] = fmaf(z, Gi[rp][NQ + qg + j], acc[j]);
        }
        #pragma unroll
        for (int j = 0; j < 4; ++j) Et[qg + j][o] = acc[j];
    }
    __syncthreads();

    {
        __hip_bfloat16* P2b = P2 + (size_t)b * KFC;
        int ti = wv >> 1;
        int tj0 = (wv & 1) * 2;
        int r8 = (l >> 5) * 8;
        int rm = l & 31;

        short8 afr;
        {
            __hip_bfloat16* ah = (__hip_bfloat16*)&afr;
            #pragma unroll
            for (int j = 0; j < 8; ++j)
                ah[j] = __float2bfloat16(Et[r8 + j][ti * 32 + rm]);
        }
        #pragma unroll
        for (int tjo = 0; tjo < 2; ++tjo) {
            int tj = tj0 + tjo;
            short8 bfr;
            __hip_bfloat16* bh = (__hip_bfloat16*)&bfr;
            #pragma unroll
            for (int j = 0; j < 8; ++j)
                bh[j] = __float2bfloat16(Zt[r8 + j][tj * 32 + rm]);
            f32x16 cc = {};
            cc = __builtin_amdgcn_mfma_f32_32x32x16_bf16(afr, bfr, cc, 0, 0, 0);
            #pragma unroll
            for (int reg = 0; reg < 16; ++reg) {
                int row = (reg & 3) + 8 * (reg >> 2) + 4 * (l >> 5);
                P2b[(size_t)(ti * 32 + row) * D2 + tj * 32 + rm] =
                    __float2bfloat16(cc[reg]);
            }
        }
    }
}

__global__ __launch_bounds__(256) void k_fc(const __hip_bfloat16* __restrict__ P2,
                                            const __hip_bfloat16* __restrict__ fcw16,
                                            float* __restrict__ part) {
    int bt = blockIdx.x;
    int ks = blockIdx.y;
    int t  = threadIdx.x;
    int lane = t & 63;
    int w    = t >> 6;
    int m  = lane & 15;
    int kg = (lane >> 4) * 8;

    const __hip_bfloat16* pa =
        P2 + (size_t)(bt * 16 + m) * KFC + ks * KCH + kg;

    int c0 = w * 32 + m;
    int c1 = c0 + 16;
    bool v0 = (c0 < NC), v1 = (c1 < NC);
    const __hip_bfloat16* pb0 =
        fcw16 + (size_t)(v0 ? c0 : 0) * KFC + ks * KCH + kg;
    const __hip_bfloat16* pb1 =
        fcw16 + (size_t)(v1 ? c1 : 0) * KFC + ks * KCH + kg;

    f32x4 acc0 = {0.f, 0.f, 0.f, 0.f};
    f32x4 acc1 = {0.f, 0.f, 0.f, 0.f};
    short8 zz = {};

    #pragma unroll 4
    for (int s = 0; s < STEPS; ++s) {
        short8 a  = *(const short8*)(pa + s * 32);
        short8 b0 = v0 ? *(const short8*)(pb0 + s * 32) : zz;
        short8 b1 = v1 ? *(const short8*)(pb1 + s * 32) : zz;
        acc0 = __builtin_amdgcn_mfma_f32_16x16x32_bf16(a, b0, acc0, 0, 0, 0);
        acc1 = __builtin_amdgcn_mfma_f32_16x16x32_bf16(a, b1, acc1, 0, 0, 0);
    }

    int r0 = (lane >> 4) * 4;
    float* pp = part + ((size_t)ks * BATCH + bt * 16 + r0) * D2;
    #pragma unroll
    for (int j = 0; j < 4; ++j) {
        pp[(size_t)j * D2 + w * 32 + m]      = acc0[j];
        pp[(size_t)j * D2 + w * 32 + 16 + m] = acc1[j];
    }
}

__global__ __launch_bounds__(128) void k_red(const float* __restrict__ part,
                                             const float* __restrict__ fcb,
                                             float* __restrict__ out) {
    int b = blockIdx.x;
    int c = threadIdx.x;
    if (c < NC) {
        float s = fcb[c];
        #pragma unroll 8
        for (int ks = 0; ks < KS; ++ks)
            s += part[((size_t)ks * BATCH + b) * D2 + c];
        out[(size_t)b * NC + c] = s;
    }
}

extern "C" void kernel_launch(void* const* d_in, const int* in_sizes, int n_in,
                              void* d_out, int out_size, void* d_ws, size_t ws_size,
                              hipStream_t stream) {
    const float* X   = (const float*)d_in[0];   // (256, 512, 16)
    const float* W   = (const float*)d_in[1];   // (256, 512)
    const float* fcw = (const float*)d_in[2];   // (100, 16384)
    const float* fcb = (const float*)d_in[3];   // (100,)
    float* out = (float*)d_out;                 // (256, 100)

    __hip_bfloat16* W2hi  = (__hip_bfloat16*)d_ws;            // 65536 bf16
    __hip_bfloat16* W2lo  = W2hi + 65536;                     // 65536 bf16
    __hip_bfloat16* fcw16 = W2lo + 65536;                     // 1638400 bf16 (fallback only)
    __hip_bfloat16* P2b16 = fcw16 + 1638400;                  // 4194304 bf16
    float*          part  = (float*)(P2b16 + 4194304);        // 1048576 f (max of both paths)
    // total ws ~= 16.1 MB

    void* args[] = {(void*)&X, (void*)&W, (void*)&fcw, (void*)&fcb, (void*)&out,
                    (void*)&W2hi, (void*)&W2lo, (void*)&P2b16, (void*)&part};
    hipError_t err = hipLaunchCooperativeKernel((const void*)k_all,
                                                dim3(BATCH), dim3(512),
                                                args, 0, stream);
    if (err != hipSuccess) {
        // fallback: validated R8 4-kernel pipeline
        k_prep<<<dim3(CVT_BLKS + W2_BLKS), 256, 0, stream>>>(W, fcw, W2hi, W2lo, fcw16);
        k_zgep<<<dim3(BATCH), 512, 0, stream>>>(X, W2hi, W2lo, P2b16);
        k_fc  <<<dim3(16, KS), 256, 0, stream>>>(P2b16, fcw16, part);
        k_red <<<dim3(BATCH), 128, 0, stream>>>(part, fcb, out);
    }
}

// Round 10
// 104.002 us; speedup vs baseline: 2.7360x; 2.7360x over previous
//
#include <hip/hip_runtime.h>
#include <hip/hip_bf16.h>
#include <cstdint>

#define BATCH 256
#define DIN   512
#define D2    128
#define NQ    16
#define NC    100
#define KFC   (D2 * D2)      // 16384

#define KS    32             // K-splits for FC
#define KCH   (KFC / KS)     // 512
#define STEPS (KCH / 32)     // 16 MFMA K-steps per block

#define ZPAD  132            // Zt/Et row stride (floats)
#define CVT_BLKS 800
#define W2_BLKS  256

typedef short short8 __attribute__((ext_vector_type(8)));
typedef float f32x4  __attribute__((ext_vector_type(4)));
typedef float f32x16 __attribute__((ext_vector_type(16)));

static __device__ __forceinline__ unsigned short f2bf_rne(float f) {
    unsigned x = __float_as_uint(f);
    return (unsigned short)((x + 0x7fffu + ((x >> 16) & 1u)) >> 16);
}
static __device__ __forceinline__ float bf2f(unsigned short u) {
    return __uint_as_float(((unsigned)u) << 16);
}

// ---------------------------------------------------------------------------
// K1: fused prep. blocks [0,800): fcw fp32->bf16.
// blocks [800,1056): W2 row-pair-avg, bf16 hi/lo split, [o][i] layout.
// Block 800 also zeroes the FC ticket counters (runs before k_fc).
// ---------------------------------------------------------------------------
__global__ __launch_bounds__(256) void k_prep(const float* __restrict__ W,
                                              const float* __restrict__ fcw,
                                              __hip_bfloat16* __restrict__ W2hi,
                                              __hip_bfloat16* __restrict__ W2lo,
                                              __hip_bfloat16* __restrict__ fcw16,
                                              int* __restrict__ cnt) {
    int blk = blockIdx.x;
    if (blk < CVT_BLKS) {
        int i = (blk * 256 + threadIdx.x) * 8;
        float4 a = *(const float4*)(fcw + i);
        float4 b = *(const float4*)(fcw + i + 4);
        short8 v;
        __hip_bfloat16* h = (__hip_bfloat16*)&v;
        h[0] = __float2bfloat16(a.x); h[1] = __float2bfloat16(a.y);
        h[2] = __float2bfloat16(a.z); h[3] = __float2bfloat16(a.w);
        h[4] = __float2bfloat16(b.x); h[5] = __float2bfloat16(b.y);
        h[6] = __float2bfloat16(b.z); h[7] = __float2bfloat16(b.w);
        *(short8*)(fcw16 + i) = v;
    } else {
        if (blk == CVT_BLKS && threadIdx.x < 16) cnt[threadIdx.x] = 0;
        int idx = (blk - CVT_BLKS) * 256 + threadIdx.x;   // 0..65535
        int o = idx >> 9;
        int i = idx & (DIN - 1);
        float v = 0.5f * (W[(size_t)(2 * o) * DIN + i] +
                          W[(size_t)(2 * o + 1) * DIN + i]);
        unsigned short hi = f2bf_rne(v);
        unsigned short lo = f2bf_rne(v - bf2f(hi));
        *(unsigned short*)(W2hi + idx) = hi;
        *(unsigned short*)(W2lo + idx) = lo;
    }
}

// ---------------------------------------------------------------------------
// Hand-unrolled Gauss-Jordan step (all indices compile-time constant).
// ---------------------------------------------------------------------------
#define GJ_STEP(K) do {                                                   \
    float piv = __shfl(g[(K) & 7], ((K) >> 3) * 16 + (K), 64);            \
    float fac = __shfl(g[(K) & 7], ((K) >> 3) * 16 + r, 64);              \
    float inv = 1.0f / piv;                                               \
    float f   = fac * inv;                                                \
    float p0 = __shfl(g[0], cg16 + (K), 64);                              \
    float p1 = __shfl(g[1], cg16 + (K), 64);                              \
    float p2 = __shfl(g[2], cg16 + (K), 64);                              \
    float p3 = __shfl(g[3], cg16 + (K), 64);                              \
    float p4 = __shfl(g[4], cg16 + (K), 64);                              \
    float p5 = __shfl(g[5], cg16 + (K), 64);                              \
    float p6 = __shfl(g[6], cg16 + (K), 64);                              \
    float p7 = __shfl(g[7], cg16 + (K), 64);                              \
    bool isk = (r == (K));                                                \
    g[0] = isk ? p0 * inv : fmaf(-f, p0, g[0]);                           \
    g[1] = isk ? p1 * inv : fmaf(-f, p1, g[1]);                           \
    g[2] = isk ? p2 * inv : fmaf(-f, p2, g[2]);                           \
    g[3] = isk ? p3 * inv : fmaf(-f, p3, g[3]);                           \
    g[4] = isk ? p4 * inv : fmaf(-f, p4, g[4]);                           \
    g[5] = isk ? p5 * inv : fmaf(-f, p5, g[5]);                           \
    g[6] = isk ? p6 * inv : fmaf(-f, p6, g[6]);                           \
    g[7] = isk ? p7 * inv : fmaf(-f, p7, g[7]);                           \
} while (0)

// ---------------------------------------------------------------------------
// K2: per-batch pipeline, 256 blocks x 512 threads.
// stage X_b -> build MFMA B-fragments (bf16 hi/lo) in FRAG-LINEAR LDS order
// (Z-phase ds_read_b128 is lane-linear, conflict-free) -> Z via MFMA
// (hi/lo compensated) -> G -> wave-register GJ -> E -> P2 via MFMA -> bf16.
// ---------------------------------------------------------------------------
__global__ __launch_bounds__(512) void k_zgep(const float* __restrict__ X,
                                              const __hip_bfloat16* __restrict__ W2hi,
                                              const __hip_bfloat16* __restrict__ W2lo,
                                              __hip_bfloat16* __restrict__ P2) {
    __shared__ float Xs[DIN][17];               // 34.8 KB
    __shared__ unsigned int FragHi[16 * 256];   // 16 KB: [s][lane][4 dwords]
    __shared__ unsigned int FragLo[16 * 256];   // 16 KB
    __shared__ float Zt[NQ][ZPAD];
    __shared__ float Et[NQ][ZPAD];
    __shared__ float Gi[NQ][36];

    int b = blockIdx.x;
    int t = threadIdx.x;
    int l = t & 63;
    int wv = t >> 6;

    // phase 0: stage X_b (coalesced float4 reads)
    {
        const float4* src = (const float4*)(X + (size_t)b * DIN * NQ);
        #pragma unroll
        for (int r = 0; r < 4; ++r) {
            float4 v = src[t + r * 512];
            int idx = (t + r * 512) * 4;
            int i = idx >> 4, q = idx & 15;
            Xs[i][q]     = v.x;
            Xs[i][q + 1] = v.y;
            Xs[i][q + 2] = v.z;
            Xs[i][q + 3] = v.w;
        }
    }
    __syncthreads();

    // phase 0b: build fragments. Dword d of frag array holds elements
    // j=2jj,2jj+1 of lane ln, frag s:  X[i = s*32 + ((ln>>4)&3)*8 + 2jj(+1)][q=ln&15]
    #pragma unroll
    for (int it = 0; it < 8; ++it) {
        int d  = t + it * 512;          // 0..4095, LDS writes fully linear
        int s  = d >> 8;
        int ln = (d >> 2) & 63;
        int jj = d & 3;
        int q  = ln & 15;
        int i0 = s * 32 + ((ln >> 4) & 3) * 8 + jj * 2;
        float v0 = Xs[i0][q], v1 = Xs[i0 + 1][q];
        unsigned short h0 = f2bf_rne(v0), h1 = f2bf_rne(v1);
        unsigned short l0 = f2bf_rne(v0 - bf2f(h0));
        unsigned short l1 = f2bf_rne(v1 - bf2f(h1));
        FragHi[d] = (unsigned)h0 | ((unsigned)h1 << 16);
        FragLo[d] = (unsigned)l0 | ((unsigned)l1 << 16);
    }
    __syncthreads();

    // phase Z (MFMA): wave wv -> Z rows wv*16..+15.  B-frags lane-linear.
    {
        int m  = l & 15;
        int kg = (l >> 4) * 8;
        const __hip_bfloat16* whi = W2hi + (size_t)(wv * 16 + m) * DIN + kg;
        const __hip_bfloat16* wlo = W2lo + (size_t)(wv * 16 + m) * DIN + kg;
        f32x4 acc = {0.f, 0.f, 0.f, 0.f};
        #pragma unroll 4
        for (int s = 0; s < 16; ++s) {
            short8 ahi = *(const short8*)(whi + s * 32);
            short8 alo = *(const short8*)(wlo + s * 32);
            short8 bhi = *(const short8*)(&FragHi[s * 256 + l * 4]);
            short8 blo = *(const short8*)(&FragLo[s * 256 + l * 4]);
            acc = __builtin_amdgcn_mfma_f32_16x16x32_bf16(ahi, bhi, acc, 0, 0, 0);
            acc = __builtin_amdgcn_mfma_f32_16x16x32_bf16(ahi, blo, acc, 0, 0, 0);
            acc = __builtin_amdgcn_mfma_f32_16x16x32_bf16(alo, bhi, acc, 0, 0, 0);
        }
        int r0 = (l >> 4) * 4;
        #pragma unroll
        for (int j = 0; j < 4; ++j)
            Zt[m][wv * 16 + r0 + j] = acc[j];
    }
    __syncthreads();

    // phase G: G = Z^T Z, set up [G | I]
    if (t < 256) {
        int qq = t >> 4, rr = t & 15;
        float s = 0.f;
        for (int i = 0; i < D2; i += 4) {
            float4 a = *(const float4*)&Zt[qq][i];
            float4 c = *(const float4*)&Zt[rr][i];
            s = fmaf(a.x, c.x, s); s = fmaf(a.y, c.y, s);
            s = fmaf(a.z, c.z, s); s = fmaf(a.w, c.w, s);
        }
        Gi[qq][rr] = s;
        Gi[qq][NQ + rr] = (qq == rr) ? 1.f : 0.f;
    }
    __syncthreads();

    // phase GJ: wave 0 register Gauss-Jordan
    if (t < 64) {
        int r    = t & 15;
        int cgg  = t >> 4;
        int cg16 = cgg * 16;
        float g[8];
        #pragma unroll
        for (int j = 0; j < 8; ++j) g[j] = Gi[r][cgg * 8 + j];
        GJ_STEP(0);  GJ_STEP(1);  GJ_STEP(2);  GJ_STEP(3);
        GJ_STEP(4);  GJ_STEP(5);  GJ_STEP(6);  GJ_STEP(7);
        GJ_STEP(8);  GJ_STEP(9);  GJ_STEP(10); GJ_STEP(11);
        GJ_STEP(12); GJ_STEP(13); GJ_STEP(14); GJ_STEP(15);
        if (cgg >= 2) {
            #pragma unroll
            for (int j = 0; j < 8; ++j) Gi[r][cgg * 8 + j] = g[j];
        }
    }
    __syncthreads();

    // phase E: E = Z G^{-1}
    {
        int o  = t & (D2 - 1);
        int qg = (t >> 7) * 4;
        float acc[4] = {};
        #pragma unroll
        for (int rp = 0; rp < NQ; ++rp) {
            float z = Zt[rp][o];
            #pragma unroll
            for (int j = 0; j < 4; ++j)
                acc[j] = fmaf(z, Gi[rp][NQ + qg + j], acc[j]);
        }
        #pragma unroll
        for (int j = 0; j < 4; ++j) Et[qg + j][o] = acc[j];
    }
    __syncthreads();

    // phase P2 (MFMA 32x32x16): P2[i][j] = sum_r Et[r][i] * Zt[r][j]
    {
        __hip_bfloat16* P2b = P2 + (size_t)b * KFC;
        int ti = wv >> 1;
        int tj0 = (wv & 1) * 2;
        int r8 = (l >> 5) * 8;
        int rm = l & 31;

        short8 afr;
        {
            __hip_bfloat16* ah = (__hip_bfloat16*)&afr;
            #pragma unroll
            for (int j = 0; j < 8; ++j)
                ah[j] = __float2bfloat16(Et[r8 + j][ti * 32 + rm]);
        }
        #pragma unroll
        for (int tjo = 0; tjo < 2; ++tjo) {
            int tj = tj0 + tjo;
            short8 bfr;
            __hip_bfloat16* bh = (__hip_bfloat16*)&bfr;
            #pragma unroll
            for (int j = 0; j < 8; ++j)
                bh[j] = __float2bfloat16(Zt[r8 + j][tj * 32 + rm]);
            f32x16 cc = {};
            cc = __builtin_amdgcn_mfma_f32_32x32x16_bf16(afr, bfr, cc, 0, 0, 0);
            #pragma unroll
            for (int reg = 0; reg < 16; ++reg) {
                int row = (reg & 3) + 8 * (reg >> 2) + 4 * (l >> 5);
                P2b[(size_t)(ti * 32 + row) * D2 + tj * 32 + rm] =
                    __float2bfloat16(cc[reg]);
            }
        }
    }
}

// ---------------------------------------------------------------------------
// K3: MFMA split-K FC + last-block deterministic reduce (ticket per bt).
// grid (16 bt, 32 ks) = 512 blocks.
// ---------------------------------------------------------------------------
__global__ __launch_bounds__(256) void k_fc(const __hip_bfloat16* __restrict__ P2,
                                            const __hip_bfloat16* __restrict__ fcw16,
                                            float* __restrict__ part,
                                            const float* __restrict__ fcb,
                                            float* __restrict__ out,
                                            int* __restrict__ cnt) {
    int bt = blockIdx.x;            // 0..15
    int ks = blockIdx.y;            // 0..31
    int t  = threadIdx.x;
    int lane = t & 63;
    int w    = t >> 6;
    int m  = lane & 15;
    int kg = (lane >> 4) * 8;

    const __hip_bfloat16* pa =
        P2 + (size_t)(bt * 16 + m) * KFC + ks * KCH + kg;

    int c0 = w * 32 + m;
    int c1 = c0 + 16;
    bool v0 = (c0 < NC), v1 = (c1 < NC);
    const __hip_bfloat16* pb0 =
        fcw16 + (size_t)(v0 ? c0 : 0) * KFC + ks * KCH + kg;
    const __hip_bfloat16* pb1 =
        fcw16 + (size_t)(v1 ? c1 : 0) * KFC + ks * KCH + kg;

    f32x4 acc0 = {0.f, 0.f, 0.f, 0.f};
    f32x4 acc1 = {0.f, 0.f, 0.f, 0.f};
    short8 zz = {};

    #pragma unroll 4
    for (int s = 0; s < STEPS; ++s) {
        short8 a  = *(const short8*)(pa + s * 32);
        short8 b0 = v0 ? *(const short8*)(pb0 + s * 32) : zz;
        short8 b1 = v1 ? *(const short8*)(pb1 + s * 32) : zz;
        acc0 = __builtin_amdgcn_mfma_f32_16x16x32_bf16(a, b0, acc0, 0, 0, 0);
        acc1 = __builtin_amdgcn_mfma_f32_16x16x32_bf16(a, b1, acc1, 0, 0, 0);
    }

    int r0 = (lane >> 4) * 4;
    float* pp = part + ((size_t)ks * BATCH + bt * 16 + r0) * D2;
    #pragma unroll
    for (int j = 0; j < 4; ++j) {
        pp[(size_t)j * D2 + w * 32 + m]      = acc0[j];
        pp[(size_t)j * D2 + w * 32 + 16 + m] = acc1[j];
    }

    // ------- last-block ticket: the 32nd ks-block for this bt reduces -------
    __threadfence();                          // make part writes visible
    __shared__ int lastFlag;
    if (t == 0) lastFlag = (atomicAdd(&cnt[bt], 1) == KS - 1);
    __syncthreads();
    if (lastFlag) {
        __threadfence();                      // see all other blocks' writes
        for (int idx = t; idx < 16 * NC; idx += 256) {
            int bl = idx / NC;                // 0..15
            int c  = idx - bl * NC;           // 0..99
            float s = fcb[c];
            #pragma unroll 8
            for (int k2 = 0; k2 < KS; ++k2)
                s += part[((size_t)k2 * BATCH + bt * 16 + bl) * D2 + c];
            out[(size_t)(bt * 16 + bl) * NC + c] = s;
        }
    }
}

extern "C" void kernel_launch(void* const* d_in, const int* in_sizes, int n_in,
                              void* d_out, int out_size, void* d_ws, size_t ws_size,
                              hipStream_t stream) {
    const float* X   = (const float*)d_in[0];   // (256, 512, 16)
    const float* W   = (const float*)d_in[1];   // (256, 512)
    const float* fcw = (const float*)d_in[2];   // (100, 16384)
    const float* fcb = (const float*)d_in[3];   // (100,)
    float* out = (float*)d_out;                 // (256, 100)

    __hip_bfloat16* W2hi  = (__hip_bfloat16*)d_ws;            // 65536 bf16
    __hip_bfloat16* W2lo  = W2hi + 65536;                     // 65536 bf16
    __hip_bfloat16* fcw16 = W2lo + 65536;                     // 1638400 bf16
    __hip_bfloat16* P2b16 = fcw16 + 1638400;                  // 4194304 bf16
    float*          part  = (float*)(P2b16 + 4194304);        // 1048576 f (4 MB)
    int*            cnt   = (int*)(part + 1048576);           // 16 ints
    // total ws ~= 16.1 MB

    k_prep<<<dim3(CVT_BLKS + W2_BLKS), 256, 0, stream>>>(W, fcw, W2hi, W2lo, fcw16, cnt);
    k_zgep<<<dim3(BATCH), 512, 0, stream>>>(X, W2hi, W2lo, P2b16);
    k_fc  <<<dim3(16, KS), 256, 0, stream>>>(P2b16, fcw16, part, fcb, out, cnt);
}

// Round 11
// 43.974 us; speedup vs baseline: 6.4709x; 2.3651x over previous
//
#include <hip/hip_runtime.h>
#include <hip/hip_bf16.h>
#include <cstdint>

#define BATCH 256
#define DIN   512
#define D2    128
#define NQ    16
#define NC    100
#define KFC   (D2 * D2)      // 16384

#define KS    32             // K-splits for FC
#define KCH   (KFC / KS)     // 512
#define STEPS (KCH / 32)     // 16 MFMA K-steps per block

#define ZPAD  132            // Zt/Et row stride (floats)
#define CVT_BLKS  800        // k_prep: fcw cvt blocks
#define W2_BLKS   256        // k_prep: W2 hi/lo blocks
#define BIAS_BLKS 100        // k_prep: out = bias init blocks (25600/256)

typedef short short8 __attribute__((ext_vector_type(8)));
typedef float f32x4  __attribute__((ext_vector_type(4)));
typedef float f32x16 __attribute__((ext_vector_type(16)));

static __device__ __forceinline__ unsigned short f2bf_rne(float f) {
    unsigned x = __float_as_uint(f);
    return (unsigned short)((x + 0x7fffu + ((x >> 16) & 1u)) >> 16);
}
static __device__ __forceinline__ float bf2f(unsigned short u) {
    return __uint_as_float(((unsigned)u) << 16);
}

// ---------------------------------------------------------------------------
// K1: fused prep.
//   blocks [0,800):        fcw fp32 -> bf16
//   blocks [800,1056):     W2 = row-pair-avg of W, bf16 hi/lo split, [o][i]
//   blocks [1056,1156):    out[b][c] = fcb[c]  (bias init for k_fc atomics)
// ---------------------------------------------------------------------------
__global__ __launch_bounds__(256) void k_prep(const float* __restrict__ W,
                                              const float* __restrict__ fcw,
                                              const float* __restrict__ fcb,
                                              __hip_bfloat16* __restrict__ W2hi,
                                              __hip_bfloat16* __restrict__ W2lo,
                                              __hip_bfloat16* __restrict__ fcw16,
                                              float* __restrict__ out) {
    int blk = blockIdx.x;
    if (blk < CVT_BLKS) {
        int i = (blk * 256 + threadIdx.x) * 8;
        float4 a = *(const float4*)(fcw + i);
        float4 b = *(const float4*)(fcw + i + 4);
        short8 v;
        __hip_bfloat16* h = (__hip_bfloat16*)&v;
        h[0] = __float2bfloat16(a.x); h[1] = __float2bfloat16(a.y);
        h[2] = __float2bfloat16(a.z); h[3] = __float2bfloat16(a.w);
        h[4] = __float2bfloat16(b.x); h[5] = __float2bfloat16(b.y);
        h[6] = __float2bfloat16(b.z); h[7] = __float2bfloat16(b.w);
        *(short8*)(fcw16 + i) = v;
    } else if (blk < CVT_BLKS + W2_BLKS) {
        int idx = (blk - CVT_BLKS) * 256 + threadIdx.x;   // 0..65535
        int o = idx >> 9;
        int i = idx & (DIN - 1);
        float v = 0.5f * (W[(size_t)(2 * o) * DIN + i] +
                          W[(size_t)(2 * o + 1) * DIN + i]);
        unsigned short hi = f2bf_rne(v);
        unsigned short lo = f2bf_rne(v - bf2f(hi));
        *(unsigned short*)(W2hi + idx) = hi;
        *(unsigned short*)(W2lo + idx) = lo;
    } else {
        int idx = (blk - CVT_BLKS - W2_BLKS) * 256 + threadIdx.x;  // 0..25599
        int c = idx % NC;
        out[idx] = fcb[c];
    }
}

// ---------------------------------------------------------------------------
// Hand-unrolled Gauss-Jordan step (all indices compile-time constant).
// ---------------------------------------------------------------------------
#define GJ_STEP(K) do {                                                   \
    float piv = __shfl(g[(K) & 7], ((K) >> 3) * 16 + (K), 64);            \
    float fac = __shfl(g[(K) & 7], ((K) >> 3) * 16 + r, 64);              \
    float inv = 1.0f / piv;                                               \
    float f   = fac * inv;                                                \
    float p0 = __shfl(g[0], cg16 + (K), 64);                              \
    float p1 = __shfl(g[1], cg16 + (K), 64);                              \
    float p2 = __shfl(g[2], cg16 + (K), 64);                              \
    float p3 = __shfl(g[3], cg16 + (K), 64);                              \
    float p4 = __shfl(g[4], cg16 + (K), 64);                              \
    float p5 = __shfl(g[5], cg16 + (K), 64);                              \
    float p6 = __shfl(g[6], cg16 + (K), 64);                              \
    float p7 = __shfl(g[7], cg16 + (K), 64);                              \
    bool isk = (r == (K));                                                \
    g[0] = isk ? p0 * inv : fmaf(-f, p0, g[0]);                           \
    g[1] = isk ? p1 * inv : fmaf(-f, p1, g[1]);                           \
    g[2] = isk ? p2 * inv : fmaf(-f, p2, g[2]);                           \
    g[3] = isk ? p3 * inv : fmaf(-f, p3, g[3]);                           \
    g[4] = isk ? p4 * inv : fmaf(-f, p4, g[4]);                           \
    g[5] = isk ? p5 * inv : fmaf(-f, p5, g[5]);                           \
    g[6] = isk ? p6 * inv : fmaf(-f, p6, g[6]);                           \
    g[7] = isk ? p7 * inv : fmaf(-f, p7, g[7]);                           \
} while (0)

// ---------------------------------------------------------------------------
// K2: per-batch pipeline, 256 blocks x 512 threads (unchanged from R10;
// frag-linear LDS, conflict-free Z-phase reads).
// ---------------------------------------------------------------------------
__global__ __launch_bounds__(512) void k_zgep(const float* __restrict__ X,
                                              const __hip_bfloat16* __restrict__ W2hi,
                                              const __hip_bfloat16* __restrict__ W2lo,
                                              __hip_bfloat16* __restrict__ P2) {
    __shared__ float Xs[DIN][17];
    __shared__ unsigned int FragHi[16 * 256];
    __shared__ unsigned int FragLo[16 * 256];
    __shared__ float Zt[NQ][ZPAD];
    __shared__ float Et[NQ][ZPAD];
    __shared__ float Gi[NQ][36];

    int b = blockIdx.x;
    int t = threadIdx.x;
    int l = t & 63;
    int wv = t >> 6;

    // phase 0: stage X_b
    {
        const float4* src = (const float4*)(X + (size_t)b * DIN * NQ);
        #pragma unroll
        for (int r = 0; r < 4; ++r) {
            float4 v = src[t + r * 512];
            int idx = (t + r * 512) * 4;
            int i = idx >> 4, q = idx & 15;
            Xs[i][q]     = v.x;
            Xs[i][q + 1] = v.y;
            Xs[i][q + 2] = v.z;
            Xs[i][q + 3] = v.w;
        }
    }
    __syncthreads();

    // phase 0b: build MFMA B-fragments (hi/lo), LDS writes fully linear
    #pragma unroll
    for (int it = 0; it < 8; ++it) {
        int d  = t + it * 512;
        int s  = d >> 8;
        int ln = (d >> 2) & 63;
        int jj = d & 3;
        int q  = ln & 15;
        int i0 = s * 32 + ((ln >> 4) & 3) * 8 + jj * 2;
        float v0 = Xs[i0][q], v1 = Xs[i0 + 1][q];
        unsigned short h0 = f2bf_rne(v0), h1 = f2bf_rne(v1);
        unsigned short l0 = f2bf_rne(v0 - bf2f(h0));
        unsigned short l1 = f2bf_rne(v1 - bf2f(h1));
        FragHi[d] = (unsigned)h0 | ((unsigned)h1 << 16);
        FragLo[d] = (unsigned)l0 | ((unsigned)l1 << 16);
    }
    __syncthreads();

    // phase Z (MFMA): hi/lo compensated
    {
        int m  = l & 15;
        int kg = (l >> 4) * 8;
        const __hip_bfloat16* whi = W2hi + (size_t)(wv * 16 + m) * DIN + kg;
        const __hip_bfloat16* wlo = W2lo + (size_t)(wv * 16 + m) * DIN + kg;
        f32x4 acc = {0.f, 0.f, 0.f, 0.f};
        #pragma unroll 4
        for (int s = 0; s < 16; ++s) {
            short8 ahi = *(const short8*)(whi + s * 32);
            short8 alo = *(const short8*)(wlo + s * 32);
            short8 bhi = *(const short8*)(&FragHi[s * 256 + l * 4]);
            short8 blo = *(const short8*)(&FragLo[s * 256 + l * 4]);
            acc = __builtin_amdgcn_mfma_f32_16x16x32_bf16(ahi, bhi, acc, 0, 0, 0);
            acc = __builtin_amdgcn_mfma_f32_16x16x32_bf16(ahi, blo, acc, 0, 0, 0);
            acc = __builtin_amdgcn_mfma_f32_16x16x32_bf16(alo, bhi, acc, 0, 0, 0);
        }
        int r0 = (l >> 4) * 4;
        #pragma unroll
        for (int j = 0; j < 4; ++j)
            Zt[m][wv * 16 + r0 + j] = acc[j];
    }
    __syncthreads();

    // phase G: G = Z^T Z
    if (t < 256) {
        int qq = t >> 4, rr = t & 15;
        float s = 0.f;
        for (int i = 0; i < D2; i += 4) {
            float4 a = *(const float4*)&Zt[qq][i];
            float4 c = *(const float4*)&Zt[rr][i];
            s = fmaf(a.x, c.x, s); s = fmaf(a.y, c.y, s);
            s = fmaf(a.z, c.z, s); s = fmaf(a.w, c.w, s);
        }
        Gi[qq][rr] = s;
        Gi[qq][NQ + rr] = (qq == rr) ? 1.f : 0.f;
    }
    __syncthreads();

    // phase GJ: wave 0 register Gauss-Jordan
    if (t < 64) {
        int r    = t & 15;
        int cgg  = t >> 4;
        int cg16 = cgg * 16;
        float g[8];
        #pragma unroll
        for (int j = 0; j < 8; ++j) g[j] = Gi[r][cgg * 8 + j];
        GJ_STEP(0);  GJ_STEP(1);  GJ_STEP(2);  GJ_STEP(3);
        GJ_STEP(4);  GJ_STEP(5);  GJ_STEP(6);  GJ_STEP(7);
        GJ_STEP(8);  GJ_STEP(9);  GJ_STEP(10); GJ_STEP(11);
        GJ_STEP(12); GJ_STEP(13); GJ_STEP(14); GJ_STEP(15);
        if (cgg >= 2) {
            #pragma unroll
            for (int j = 0; j < 8; ++j) Gi[r][cgg * 8 + j] = g[j];
        }
    }
    __syncthreads();

    // phase E: E = Z G^{-1}
    {
        int o  = t & (D2 - 1);
        int qg = (t >> 7) * 4;
        float acc[4] = {};
        #pragma unroll
        for (int rp = 0; rp < NQ; ++rp) {
            float z = Zt[rp][o];
            #pragma unroll
            for (int j = 0; j < 4; ++j)
                acc[j] = fmaf(z, Gi[rp][NQ + qg + j], acc[j]);
        }
        #pragma unroll
        for (int j = 0; j < 4; ++j) Et[qg + j][o] = acc[j];
    }
    __syncthreads();

    // phase P2 (MFMA 32x32x16): P2[i][j] = sum_r Et[r][i] * Zt[r][j]
    {
        __hip_bfloat16* P2b = P2 + (size_t)b * KFC;
        int ti = wv >> 1;
        int tj0 = (wv & 1) * 2;
        int r8 = (l >> 5) * 8;
        int rm = l & 31;

        short8 afr;
        {
            __hip_bfloat16* ah = (__hip_bfloat16*)&afr;
            #pragma unroll
            for (int j = 0; j < 8; ++j)
                ah[j] = __float2bfloat16(Et[r8 + j][ti * 32 + rm]);
        }
        #pragma unroll
        for (int tjo = 0; tjo < 2; ++tjo) {
            int tj = tj0 + tjo;
            short8 bfr;
            __hip_bfloat16* bh = (__hip_bfloat16*)&bfr;
            #pragma unroll
            for (int j = 0; j < 8; ++j)
                bh[j] = __float2bfloat16(Zt[r8 + j][tj * 32 + rm]);
            f32x16 cc = {};
            cc = __builtin_amdgcn_mfma_f32_32x32x16_bf16(afr, bfr, cc, 0, 0, 0);
            #pragma unroll
            for (int reg = 0; reg < 16; ++reg) {
                int row = (reg & 3) + 8 * (reg >> 2) + 4 * (l >> 5);
                P2b[(size_t)(ti * 32 + row) * D2 + tj * 32 + rm] =
                    __float2bfloat16(cc[reg]);
            }
        }
    }
}

// ---------------------------------------------------------------------------
// K3: MFMA split-K FC, accumulating straight into out via fp32 atomicAdd
// (out pre-initialized with bias by k_prep). No fences, no tickets.
// grid (16 bt, 32 ks) = 512 blocks.
// ---------------------------------------------------------------------------
__global__ __launch_bounds__(256) void k_fc(const __hip_bfloat16* __restrict__ P2,
                                            const __hip_bfloat16* __restrict__ fcw16,
                                            float* __restrict__ out) {
    int bt = blockIdx.x;            // 0..15
    int ks = blockIdx.y;            // 0..31
    int t  = threadIdx.x;
    int lane = t & 63;
    int w    = t >> 6;
    int m  = lane & 15;
    int kg = (lane >> 4) * 8;

    const __hip_bfloat16* pa =
        P2 + (size_t)(bt * 16 + m) * KFC + ks * KCH + kg;

    int c0 = w * 32 + m;
    int c1 = c0 + 16;
    bool v0 = (c0 < NC), v1 = (c1 < NC);
    const __hip_bfloat16* pb0 =
        fcw16 + (size_t)(v0 ? c0 : 0) * KFC + ks * KCH + kg;
    const __hip_bfloat16* pb1 =
        fcw16 + (size_t)(v1 ? c1 : 0) * KFC + ks * KCH + kg;

    f32x4 acc0 = {0.f, 0.f, 0.f, 0.f};
    f32x4 acc1 = {0.f, 0.f, 0.f, 0.f};
    short8 zz = {};

    #pragma unroll 4
    for (int s = 0; s < STEPS; ++s) {
        short8 a  = *(const short8*)(pa + s * 32);
        short8 b0 = v0 ? *(const short8*)(pb0 + s * 32) : zz;
        short8 b1 = v1 ? *(const short8*)(pb1 + s * 32) : zz;
        acc0 = __builtin_amdgcn_mfma_f32_16x16x32_bf16(a, b0, acc0, 0, 0, 0);
        acc1 = __builtin_amdgcn_mfma_f32_16x16x32_bf16(a, b1, acc1, 0, 0, 0);
    }

    int r0 = (lane >> 4) * 4;
    int b0 = bt * 16 + r0;
    #pragma unroll
    for (int j = 0; j < 4; ++j) {
        if (v0) atomicAdd(&out[(size_t)(b0 + j) * NC + c0], acc0[j]);
        if (v1) atomicAdd(&out[(size_t)(b0 + j) * NC + c1], acc1[j]);
    }
}

extern "C" void kernel_launch(void* const* d_in, const int* in_sizes, int n_in,
                              void* d_out, int out_size, void* d_ws, size_t ws_size,
                              hipStream_t stream) {
    const float* X   = (const float*)d_in[0];   // (256, 512, 16)
    const float* W   = (const float*)d_in[1];   // (256, 512)
    const float* fcw = (const float*)d_in[2];   // (100, 16384)
    const float* fcb = (const float*)d_in[3];   // (100,)
    float* out = (float*)d_out;                 // (256, 100)

    __hip_bfloat16* W2hi  = (__hip_bfloat16*)d_ws;            // 65536 bf16
    __hip_bfloat16* W2lo  = W2hi + 65536;                     // 65536 bf16
    __hip_bfloat16* fcw16 = W2lo + 65536;                     // 1638400 bf16
    __hip_bfloat16* P2b16 = fcw16 + 1638400;                  // 4194304 bf16
    // total ws ~= 12.1 MB

    k_prep<<<dim3(CVT_BLKS + W2_BLKS + BIAS_BLKS), 256, 0, stream>>>(
        W, fcw, fcb, W2hi, W2lo, fcw16, out);
    k_zgep<<<dim3(BATCH), 512, 0, stream>>>(X, W2hi, W2lo, P2b16);
    k_fc  <<<dim3(16, KS), 256, 0, stream>>>(P2b16, fcw16, out);
}